// Round 6
// baseline (170.600 us; speedup 1.0000x reference)
//
#include <hip/hip_runtime.h>
#include <hip/hip_bf16.h>
#include <math.h>

// ---------------- problem constants ----------------
namespace {
constexpr int BATCH = 4;
constexpr int IMG   = 192;
constexpr int PL    = IMG * IMG;
constexpr int NP1   = 4096;   // 64*64 full-res patches per image
constexpr int MALL  = 5376;   // 4096 + 1024 + 256 candidate patches
constexpr int RS    = 28;     // fp32 row stride: 27 values + |c|^2 slot
constexpr int NCHUNK = 21;    // m-chunks for argmin partials
constexpr int TPC    = 16;    // 16-wide m-tiles per chunk (21*16*16 = 5376)

// gaussian kernel constants (float32 images of the numpy float32 values)
#define GA 0.27406862f   // gauss1d(1.0) edge
#define GB 0.45186276f   // gauss1d(1.0) center
#define RC 0.33277732f   // gauss1d(10.0) edge
#define RD 0.33444537f   // gauss1d(10.0) center

typedef __bf16 bf16x8 __attribute__((ext_vector_type(8)));
typedef float  f32x4  __attribute__((ext_vector_type(4)));

__device__ __forceinline__ void conv3(const float in[9], const float k[9], float out[9]) {
#pragma unroll
  for (int y = 0; y < 3; ++y)
#pragma unroll
    for (int x = 0; x < 3; ++x) {
      float s = 0.f;
#pragma unroll
      for (int i = 0; i < 3; ++i) {
        int yy = y + i - 1;
        if (yy < 0 || yy > 2) continue;
#pragma unroll
        for (int j = 0; j < 3; ++j) {
          int xx = x + j - 1;
          if (xx < 0 || xx > 2) continue;
          s = fmaf(k[i * 3 + j], in[yy * 3 + xx], s);
        }
      }
      out[y * 3 + x] = s;
    }
}

// gray -> normalized structure-tensor 27-vector + |c|^2 of the normalized vec
__device__ __forceinline__ void st_from_gray(const float gray[9], float stv[27], float& cs) {
  const float KX[9] = {GA * GA, 0.f, -GA * GA, GB * GA, 0.f, -GB * GA, GA * GA, 0.f, -GA * GA};
  const float KY[9] = {GA * GA, GA * GB, GA * GA, 0.f, 0.f, 0.f, -GA * GA, -GA * GB, -GA * GA};
  const float KS[9] = {RC * RC, RC * RD, RC * RC, RD * RC, RD * RD, RD * RC, RC * RC, RC * RD, RC * RC};
  float Ix[9], Iy[9];
  conv3(gray, KX, Ix);
  conv3(gray, KY, Iy);
  float Pxx[9], Pyy[9], Pxy[9];
#pragma unroll
  for (int t = 0; t < 9; ++t) {
    Pxx[t] = Ix[t] * Ix[t];
    Pyy[t] = Iy[t] * Iy[t];
    Pxy[t] = Ix[t] * Iy[t];
  }
  conv3(Pxx, KS, stv + 0);
  conv3(Pyy, KS, stv + 9);
  conv3(Pxy, KS, stv + 18);
  float s2 = 0.f;
#pragma unroll
  for (int d = 0; d < 27; ++d) s2 = fmaf(stv[d], stv[d], s2);
  float inv = 1.0f / (sqrtf(s2) + 1e-12f);
  float c = 0.f;
#pragma unroll
  for (int d = 0; d < 27; ++d) {
    stv[d] *= inv;
    c = fmaf(stv[d], stv[d], c);
  }
  cs = c;
}

// ---------------- bicubic taps (jax.image.resize, antialias=False) ----------------
__device__ __forceinline__ void mkw(int k0, int IS, float w[4], int k[4]) {
  const float W4[4] = {-0.0625f, 0.5625f, 0.5625f, -0.0625f};
  float ssum = 0.f;
#pragma unroll
  for (int u = 0; u < 4; ++u) {
    int kk = k0 + u;
    bool v = (kk >= 0) && (kk < IS);
    w[u] = v ? W4[u] : 0.f;
    k[u] = v ? kk : 0;
    ssum += w[u];
  }
  float inv = 1.f / ssum;  // interior: exactly 1.0
#pragma unroll
  for (int u = 0; u < 4; ++u) w[u] *= inv;
}

// resized-grayscale pixel straight from the 3-channel 192x192 image
// (resize and grayscale are both linear -> they commute; validated round 3, absmax 0)
__device__ __forceinline__ float bicubic_gray(const float* __restrict__ im,
                                              int i, int j, int step, int koff) {
  float wr[4], wc[4];
  int kr[4], kc[4];
  mkw(step * i + koff, IMG, wr, kr);
  mkw(step * j + koff, IMG, wc, kc);
  float acc = 0.f;
#pragma unroll
  for (int u = 0; u < 4; ++u) {
    float rs = 0.f;
#pragma unroll
    for (int v = 0; v < 4; ++v) {
      int o = kr[u] * IMG + kc[v];
      float gy = fmaf(0.114f, im[2 * PL + o], fmaf(0.587f, im[PL + o], 0.2989f * im[o]));
      rs = fmaf(wc[v], gy, rs);
    }
    acc = fmaf(wr[u], rs, acc);
  }
  return acc;
}

// ---------------- fragment-major bf16 hi/lo pack ----------------
// Tile = 16 rows = 512 uints (2 KB): hi half uints 0..255, lo half 256..511.
// Row rl, k-group lg -> uint4 at (lg*16+rl)*4 (hi) / 256+(lg*16+rl)*4 (lo).
// In argmin, lane l reads uint4 at tile_base + l*4 -> fully coalesced.
__device__ __forceinline__ void pack_row_frag(const float* __restrict__ v, float tail,
                                              unsigned* __restrict__ base, int rl) {
  unsigned uh[16], ul[16];
#pragma unroll
  for (int p = 0; p < 16; ++p) {
    float a  = (2 * p < 27) ? v[2 * p] : 0.f;
    float bb = (2 * p + 1 < 27) ? v[2 * p + 1] : (2 * p + 1 == 27 ? tail : 0.f);
    __hip_bfloat16 ah = __float2bfloat16(a);
    __hip_bfloat16 bh = __float2bfloat16(bb);
    float af = __bfloat162float(ah), bf2 = __bfloat162float(bh);
    __hip_bfloat16 al = __float2bfloat16(a - af);
    __hip_bfloat16 bl = __float2bfloat16(bb - bf2);
    uh[p] = ((unsigned)__builtin_bit_cast(unsigned short, bh) << 16) |
            (unsigned)__builtin_bit_cast(unsigned short, ah);
    ul[p] = ((unsigned)__builtin_bit_cast(unsigned short, bl) << 16) |
            (unsigned)__builtin_bit_cast(unsigned short, al);
  }
#pragma unroll
  for (int lg = 0; lg < 4; ++lg) {
    *reinterpret_cast<uint4*>(base + (size_t)(lg * 16 + rl) * 4) =
        make_uint4(uh[4 * lg], uh[4 * lg + 1], uh[4 * lg + 2], uh[4 * lg + 3]);
    *reinterpret_cast<uint4*>(base + 256 + (size_t)(lg * 16 + rl) * 4) =
        make_uint4(ul[4 * lg], ul[4 * lg + 1], ul[4 * lg + 2], ul[4 * lg + 3]);
  }
}

__device__ __forceinline__ void store_row28(float* __restrict__ dst, const float v[27], float tail) {
  float4* d4 = reinterpret_cast<float4*>(dst);
#pragma unroll
  for (int i = 0; i < 6; ++i)
    d4[i] = make_float4(v[4 * i], v[4 * i + 1], v[4 * i + 2], v[4 * i + 3]);
  d4[6] = make_float4(v[24], v[25], v[26], tail);
}

// ---------------- K1: fused front end (block-range dispatch, one st per thread) ----
// bid [0,64):    main-scale x patches  -> p1 rows
// bid [64,128):  main-scale gt patches -> p2c rows + Cp tiles
// bid [128,144): 96-scale gt patches (inline bicubic) -> p2c + Cp
// bid [144,148): 48-scale gt patches -> p2c + Cp
__global__ void __launch_bounds__(256) prep_all_kernel(
    const float* __restrict__ x, const float* __restrict__ gt,
    float* __restrict__ p1, float* __restrict__ p2c,
    unsigned* __restrict__ Cp, unsigned* __restrict__ ctr) {
  const int bid = blockIdx.x;
  const int t = threadIdx.x;
  if (bid == 0 && t == 0) ctr[0] = 0;  // reset finalize ticket (stream-ordered)

  if (bid < 128) {
    const bool isx = bid < 64;
    const int gid = (isx ? bid : bid - 64) * 256 + t;  // [0, 16384)
    const int b = gid >> 12, p = gid & (NP1 - 1);
    const int hb = p >> 6, wb = p & 63;
    const float* base = (isx ? x : gt) + (size_t)b * 3 * PL + (size_t)(hb * 3) * IMG + wb * 3;
    float gr[9];
#pragma unroll
    for (int y = 0; y < 3; ++y)
#pragma unroll
      for (int xx = 0; xx < 3; ++xx) {
        int o = y * IMG + xx;
        gr[y * 3 + xx] = fmaf(0.114f, base[2 * PL + o],
                              fmaf(0.587f, base[PL + o], 0.2989f * base[o]));
      }
    float s[27];
    float cs;
    st_from_gray(gr, s, cs);
    if (isx) {
      store_row28(p1 + (size_t)gid * RS, s, cs);
    } else {
      size_t crow = (size_t)b * MALL + p;
      store_row28(p2c + crow * RS, s, cs);
      pack_row_frag(s, -cs, Cp + (crow >> 4) * 512, (int)(crow & 15));
    }
  } else {
    int row;
    float gr[9];
    if (bid < 144) {
      int q = (bid - 128) * 256 + t;  // [0, 4096)
      int b = q >> 10, p = q & 1023;
      int hb = p >> 5, wb = p & 31;
      const float* im = gt + (size_t)b * 3 * PL;
#pragma unroll
      for (int y = 0; y < 3; ++y)
#pragma unroll
        for (int xx = 0; xx < 3; ++xx)
          gr[y * 3 + xx] = bicubic_gray(im, 3 * hb + y, 3 * wb + xx, 2, -1);
      row = b * MALL + NP1 + p;
    } else {
      int q = (bid - 144) * 256 + t;  // [0, 1024)
      int b = q >> 8, p = q & 255;
      int hb = p >> 4, wb = p & 15;
      const float* im = gt + (size_t)b * 3 * PL;
#pragma unroll
      for (int y = 0; y < 3; ++y)
#pragma unroll
        for (int xx = 0; xx < 3; ++xx)
          gr[y * 3 + xx] = bicubic_gray(im, 3 * hb + y, 3 * wb + xx, 4, 0);
      row = b * MALL + NP1 + 1024 + p;
    }
    float s[27];
    float cs;
    st_from_gray(gr, s, cs);
    store_row28(p2c + (size_t)row * RS, s, cs);
    pack_row_frag(s, -cs, Cp + ((size_t)row >> 4) * 512, row & 15);
  }
}

// ---------------- K2: pack Q = p1 + p2 (needs both -> separate kernel) ------------
__global__ void __launch_bounds__(256) pack_q_kernel(
    const float* __restrict__ p1, const float* __restrict__ p2c,
    unsigned* __restrict__ Qp) {
  int gid = blockIdx.x * 256 + threadIdx.x;  // [0, 16384)
  int b = gid >> 12, n = gid & (NP1 - 1);
  const float* a = p1 + (size_t)gid * RS;
  const float* c = p2c + ((size_t)b * MALL + n) * RS;
  float v[27];
#pragma unroll
  for (int d = 0; d < 27; ++d) v[d] = a[d] + c[d];
  pack_row_frag(v, 1.0f, Qp + (size_t)(gid >> 4) * 512, gid & 15);
}

// ---------------- K3: MFMA argmax of t = 4 + q.c - |c|^2 via packed keys ----------
// 256-thread blocks, 4 waves; wave w owns rows nbase..nbase+63 (4 n-tiles).
// Grid (16, NCHUNK, BATCH). D mapping (16x16x32): col=lane&15 (m), row=(lane>>4)*4+reg.
// key = (bits(score+4) & ~31) | (TPC-1-iter): v_max_u32 running argmax; earlier
// iter wins ties => first-argmin semantics after chunk combine. Prefetch-1 pipeline.
__global__ void __launch_bounds__(256, 4) argmin_mfma_kernel(
    const unsigned* __restrict__ Qp, const unsigned* __restrict__ Cp,
    unsigned* __restrict__ pkey, int* __restrict__ pidx) {
  const int lane = threadIdx.x & 63;
  const int w = threadIdx.x >> 6;
  const int chunk = blockIdx.y;
  const int b = blockIdx.z;
  const int nbase = blockIdx.x * 256 + w * 64;
  const int lm = lane & 15, lg = lane >> 4;

  bf16x8 qh[4], ql[4];
#pragma unroll
  for (int t = 0; t < 4; ++t) {
    const unsigned* tb = Qp + (size_t)((b * NP1 + nbase) >> 4) * 512 + (size_t)t * 512 + lane * 4;
    qh[t] = *reinterpret_cast<const bf16x8*>(tb);
    ql[t] = *reinterpret_cast<const bf16x8*>(tb + 256);
  }

  unsigned keys[4][4];
#pragma unroll
  for (int t = 0; t < 4; ++t)
#pragma unroll
    for (int r = 0; r < 4; ++r) keys[t][r] = 0u;

  const int tile0 = chunk * TPC;
  const unsigned* cb = Cp + (size_t)(b * (MALL >> 4) + tile0) * 512 + lane * 4;
  bf16x8 ch = *reinterpret_cast<const bf16x8*>(cb);
  bf16x8 cl = *reinterpret_cast<const bf16x8*>(cb + 256);
  for (int i = 0; i < TPC; ++i) {
    cb += 512;
    // prefetch next tile (last iter reads the pad tile after Cp -- harmless)
    bf16x8 nh = *reinterpret_cast<const bf16x8*>(cb);
    bf16x8 nl = *reinterpret_cast<const bf16x8*>(cb + 256);
    const unsigned tag = (unsigned)(TPC - 1 - i);
#pragma unroll
    for (int t = 0; t < 4; ++t) {
      f32x4 a = {4.f, 4.f, 4.f, 4.f};  // +4 bias: scores in [-3,2] -> positive floats
      a = __builtin_amdgcn_mfma_f32_16x16x32_bf16(qh[t], ch, a, 0, 0, 0);
      a = __builtin_amdgcn_mfma_f32_16x16x32_bf16(ql[t], ch, a, 0, 0, 0);
      a = __builtin_amdgcn_mfma_f32_16x16x32_bf16(qh[t], cl, a, 0, 0, 0);
#pragma unroll
      for (int r = 0; r < 4; ++r) {
        unsigned kb = (__builtin_bit_cast(unsigned, (float)a[r]) & 0xFFFFFFE0u) | tag;
        keys[t][r] = keys[t][r] > kb ? keys[t][r] : kb;
      }
    }
    ch = nh;
    cl = nl;
  }

  // reduce (key, m) across the 16 lanes of each row-group; min m on key ties
#pragma unroll
  for (int t = 0; t < 4; ++t)
#pragma unroll
    for (int r = 0; r < 4; ++r) {
      unsigned k = keys[t][r];
      int m = (tile0 + (int)((unsigned)(TPC - 1) - (k & 31u))) * 16 + lm;
#pragma unroll
      for (int mk = 1; mk < 16; mk <<= 1) {
        unsigned ok = (unsigned)__shfl_xor((int)k, mk, 64);
        int om = __shfl_xor(m, mk, 64);
        bool take = (ok > k) || (ok == k && om < m);
        k = take ? ok : k;
        m = take ? om : m;
      }
      if (lm == 0) {
        int row = nbase + t * 16 + lg * 4 + r;
        size_t o = ((size_t)(b * NP1 + row)) * NCHUNK + chunk;
        pkey[o] = k & 0xFFFFFFE0u;  // masked: cross-chunk strict '>' keeps earliest chunk
        pidx[o] = m;
      }
    }
}

// ---------------- K4: combine partials, gather, L1 partials, ticketed final sum ---
__global__ void __launch_bounds__(256) finalize_kernel(
    const float* __restrict__ p1, const float* __restrict__ p2c,
    const unsigned* __restrict__ pkey, const int* __restrict__ pidx,
    float* __restrict__ bsum, unsigned* __restrict__ ctr, float* __restrict__ out) {
  int g = blockIdx.x * 256 + threadIdx.x;  // [0, BATCH*NP1)
  unsigned bk = 0u;
  int bi = 0;
  for (int ms = 0; ms < NCHUNK; ++ms) {
    unsigned k = pkey[(size_t)g * NCHUNK + ms];
    int ix = pidx[(size_t)g * NCHUNK + ms];
    bool gg = k > bk;  // strict > + ascending chunks => first-argmin tie-break
    bk = gg ? k : bk;
    bi = gg ? ix : bi;
  }
  int b = g >> 12;
  const float* a = p1 + (size_t)g * RS;
  const float* s2 = p2c + ((size_t)b * MALL + bi) * RS;
  float acc = 0.f;
#pragma unroll
  for (int d = 0; d < 27; ++d) acc += fabsf(a[d] - s2[d]);

  __shared__ float red[256];
  red[threadIdx.x] = acc;
  __syncthreads();
  for (int st = 128; st > 0; st >>= 1) {
    if (threadIdx.x < st) red[threadIdx.x] += red[threadIdx.x + st];
    __syncthreads();
  }
  if (threadIdx.x == 0) {
    __hip_atomic_store(&bsum[blockIdx.x], red[0], __ATOMIC_RELEASE, __HIP_MEMORY_SCOPE_AGENT);
    unsigned prev = __hip_atomic_fetch_add(ctr, 1u, __ATOMIC_ACQ_REL, __HIP_MEMORY_SCOPE_AGENT);
    if (prev == 63) {  // last of 64 blocks: deterministic ascending-order sum
      float s = 0.f;
      for (int i = 0; i < 64; ++i)
        s += __hip_atomic_load(&bsum[i], __ATOMIC_ACQUIRE, __HIP_MEMORY_SCOPE_AGENT);
      out[0] = s * (1.0f / 442368.0f);
    }
  }
}

}  // namespace

extern "C" void kernel_launch(void* const* d_in, const int* in_sizes, int n_in,
                              void* d_out, int out_size, void* d_ws, size_t ws_size,
                              hipStream_t stream) {
  const float* x  = (const float*)d_in[0];
  const float* gt = (const float*)d_in[1];
  float* out = (float*)d_out;

  // workspace layout (4-byte slots)
  float* ws = (float*)d_ws;
  float* p1   = ws;                                              // 4*4096*28
  float* p2c  = p1 + (size_t)BATCH * NP1 * RS;                   // 4*5376*28
  unsigned* Qp = (unsigned*)(p2c + (size_t)BATCH * MALL * RS);   // 4*4096*32
  unsigned* Cp = Qp + (size_t)BATCH * NP1 * 32;                  // 4*5376*32 + 512 pad
  unsigned* pkey = Cp + (size_t)BATCH * MALL * 32 + 512;         // 4*4096*21
  int*   pidx   = (int*)(pkey + (size_t)BATCH * NP1 * NCHUNK);   // 4*4096*21
  float* bsum   = (float*)(pidx + (size_t)BATCH * NP1 * NCHUNK); // 64
  unsigned* ctr = (unsigned*)(bsum + 64);                        // 1

  // K1: fused front end (148 blocks)
  prep_all_kernel<<<148, 256, 0, stream>>>(x, gt, p1, p2c, Cp, ctr);

  // K2: Q = p1 + p2 pack (64 blocks)
  pack_q_kernel<<<64, 256, 0, stream>>>(p1, p2c, Qp);

  // K3: MFMA chunked argmax (prefetch-pipelined, coalesced fragment loads)
  {
    dim3 grid(16, NCHUNK, BATCH);
    argmin_mfma_kernel<<<grid, 256, 0, stream>>>(Qp, Cp, pkey, pidx);
  }

  // K4: combine chunks + L1 loss + ticketed deterministic final sum
  finalize_kernel<<<64, 256, 0, stream>>>(p1, p2c, pkey, pidx, bsum, ctr, out);
}

// Round 7
// 91.182 us; speedup vs baseline: 1.8710x; 1.8710x over previous
//
#include <hip/hip_runtime.h>
#include <hip/hip_bf16.h>
#include <math.h>

// ---------------- problem constants ----------------
namespace {
constexpr int BATCH = 4;
constexpr int IMG   = 192;
constexpr int PL    = IMG * IMG;
constexpr int NP1   = 4096;   // 64*64 full-res patches per image
constexpr int MALL  = 5376;   // 4096 + 1024 + 256 candidate patches
constexpr int RS    = 28;     // fp32 row stride: 27 values + |c|^2 slot
constexpr int NCHUNK = 16;    // m-chunks for argmin partials
constexpr int TPC    = 21;    // 16-wide m-tiles per chunk (16*21*16 = 5376)

// gaussian kernel constants (float32 images of the numpy float32 values)
#define GA 0.27406862f   // gauss1d(1.0) edge
#define GB 0.45186276f   // gauss1d(1.0) center
#define RC 0.33277732f   // gauss1d(10.0) edge
#define RD 0.33444537f   // gauss1d(10.0) center

typedef __bf16 bf16x8 __attribute__((ext_vector_type(8)));
typedef float  f32x4  __attribute__((ext_vector_type(4)));

__device__ __forceinline__ void conv3(const float in[9], const float k[9], float out[9]) {
#pragma unroll
  for (int y = 0; y < 3; ++y)
#pragma unroll
    for (int x = 0; x < 3; ++x) {
      float s = 0.f;
#pragma unroll
      for (int i = 0; i < 3; ++i) {
        int yy = y + i - 1;
        if (yy < 0 || yy > 2) continue;
#pragma unroll
        for (int j = 0; j < 3; ++j) {
          int xx = x + j - 1;
          if (xx < 0 || xx > 2) continue;
          s = fmaf(k[i * 3 + j], in[yy * 3 + xx], s);
        }
      }
      out[y * 3 + x] = s;
    }
}

// gray -> normalized structure-tensor 27-vector + |c|^2 of the normalized vec
__device__ __forceinline__ void st_from_gray(const float gray[9], float stv[27], float& cs) {
  const float KX[9] = {GA * GA, 0.f, -GA * GA, GB * GA, 0.f, -GB * GA, GA * GA, 0.f, -GA * GA};
  const float KY[9] = {GA * GA, GA * GB, GA * GA, 0.f, 0.f, 0.f, -GA * GA, -GA * GB, -GA * GA};
  const float KS[9] = {RC * RC, RC * RD, RC * RC, RD * RC, RD * RD, RD * RC, RC * RC, RC * RD, RC * RC};
  float Ix[9], Iy[9];
  conv3(gray, KX, Ix);
  conv3(gray, KY, Iy);
  float Pxx[9], Pyy[9], Pxy[9];
#pragma unroll
  for (int t = 0; t < 9; ++t) {
    Pxx[t] = Ix[t] * Ix[t];
    Pyy[t] = Iy[t] * Iy[t];
    Pxy[t] = Ix[t] * Iy[t];
  }
  conv3(Pxx, KS, stv + 0);
  conv3(Pyy, KS, stv + 9);
  conv3(Pxy, KS, stv + 18);
  float s2 = 0.f;
#pragma unroll
  for (int d = 0; d < 27; ++d) s2 = fmaf(stv[d], stv[d], s2);
  float inv = 1.0f / (sqrtf(s2) + 1e-12f);
  float c = 0.f;
#pragma unroll
  for (int d = 0; d < 27; ++d) {
    stv[d] *= inv;
    c = fmaf(stv[d], stv[d], c);
  }
  cs = c;
}

// ---------------- bicubic taps (jax.image.resize, antialias=False) ----------------
__device__ __forceinline__ void mkw(int k0, int IS, float w[4], int k[4]) {
  const float W4[4] = {-0.0625f, 0.5625f, 0.5625f, -0.0625f};
  float ssum = 0.f;
#pragma unroll
  for (int u = 0; u < 4; ++u) {
    int kk = k0 + u;
    bool v = (kk >= 0) && (kk < IS);
    w[u] = v ? W4[u] : 0.f;
    k[u] = v ? kk : 0;
    ssum += w[u];
  }
  float inv = 1.f / ssum;  // interior: exactly 1.0
#pragma unroll
  for (int u = 0; u < 4; ++u) w[u] *= inv;
}

// resized-grayscale pixel straight from the 3-channel 192x192 image
// (resize and grayscale are both linear -> they commute; validated, absmax 0)
__device__ __forceinline__ float bicubic_gray(const float* __restrict__ im,
                                              int i, int j, int step, int koff) {
  float wr[4], wc[4];
  int kr[4], kc[4];
  mkw(step * i + koff, IMG, wr, kr);
  mkw(step * j + koff, IMG, wc, kc);
  float acc = 0.f;
#pragma unroll
  for (int u = 0; u < 4; ++u) {
    float rs = 0.f;
#pragma unroll
    for (int v = 0; v < 4; ++v) {
      int o = kr[u] * IMG + kc[v];
      float gy = fmaf(0.114f, im[2 * PL + o], fmaf(0.587f, im[PL + o], 0.2989f * im[o]));
      rs = fmaf(wc[v], gy, rs);
    }
    acc = fmaf(wr[u], rs, acc);
  }
  return acc;
}

// ---------------- fragment-major bf16 hi/lo pack ----------------
// Tile = 16 rows = 512 uints (2 KB): hi half uints 0..255, lo half 256..511.
// Row rl, k-group lg -> uint4 at (lg*16+rl)*4 (hi) / 256+(lg*16+rl)*4 (lo).
// In argmin, lane l reads uint4 at tile_base + l*4 -> fully coalesced.
__device__ __forceinline__ void pack_row_frag(const float* __restrict__ v, float tail,
                                              unsigned* __restrict__ base, int rl) {
  unsigned uh[16], ul[16];
#pragma unroll
  for (int p = 0; p < 16; ++p) {
    float a  = (2 * p < 27) ? v[2 * p] : 0.f;
    float bb = (2 * p + 1 < 27) ? v[2 * p + 1] : (2 * p + 1 == 27 ? tail : 0.f);
    __hip_bfloat16 ah = __float2bfloat16(a);
    __hip_bfloat16 bh = __float2bfloat16(bb);
    float af = __bfloat162float(ah), bf2 = __bfloat162float(bh);
    __hip_bfloat16 al = __float2bfloat16(a - af);
    __hip_bfloat16 bl = __float2bfloat16(bb - bf2);
    uh[p] = ((unsigned)__builtin_bit_cast(unsigned short, bh) << 16) |
            (unsigned)__builtin_bit_cast(unsigned short, ah);
    ul[p] = ((unsigned)__builtin_bit_cast(unsigned short, bl) << 16) |
            (unsigned)__builtin_bit_cast(unsigned short, al);
  }
#pragma unroll
  for (int lg = 0; lg < 4; ++lg) {
    *reinterpret_cast<uint4*>(base + (size_t)(lg * 16 + rl) * 4) =
        make_uint4(uh[4 * lg], uh[4 * lg + 1], uh[4 * lg + 2], uh[4 * lg + 3]);
    *reinterpret_cast<uint4*>(base + 256 + (size_t)(lg * 16 + rl) * 4) =
        make_uint4(ul[4 * lg], ul[4 * lg + 1], ul[4 * lg + 2], ul[4 * lg + 3]);
  }
}

__device__ __forceinline__ void store_row28(float* __restrict__ dst, const float v[27], float tail) {
  float4* d4 = reinterpret_cast<float4*>(dst);
#pragma unroll
  for (int i = 0; i < 6; ++i)
    d4[i] = make_float4(v[4 * i], v[4 * i + 1], v[4 * i + 2], v[4 * i + 3]);
  d4[6] = make_float4(v[24], v[25], v[26], tail);
}

// ---------------- K1: fused front end (block-range dispatch, one st per thread) ----
// bid [0,64):    main-scale x patches  -> p1 rows
// bid [64,128):  main-scale gt patches -> p2c rows + Cp tiles
// bid [128,144): 96-scale gt patches (inline bicubic) -> p2c + Cp
// bid [144,148): 48-scale gt patches -> p2c + Cp
__global__ void __launch_bounds__(256) prep_all_kernel(
    const float* __restrict__ x, const float* __restrict__ gt,
    float* __restrict__ p1, float* __restrict__ p2c,
    unsigned* __restrict__ Cp, unsigned* __restrict__ ctr) {
  const int bid = blockIdx.x;
  const int t = threadIdx.x;
  if (bid == 0 && t == 0) ctr[0] = 0;  // reset finalize ticket (stream-ordered)

  if (bid < 128) {
    const bool isx = bid < 64;
    const int gid = (isx ? bid : bid - 64) * 256 + t;  // [0, 16384)
    const int b = gid >> 12, p = gid & (NP1 - 1);
    const int hb = p >> 6, wb = p & 63;
    const float* base = (isx ? x : gt) + (size_t)b * 3 * PL + (size_t)(hb * 3) * IMG + wb * 3;
    float gr[9];
#pragma unroll
    for (int y = 0; y < 3; ++y)
#pragma unroll
      for (int xx = 0; xx < 3; ++xx) {
        int o = y * IMG + xx;
        gr[y * 3 + xx] = fmaf(0.114f, base[2 * PL + o],
                              fmaf(0.587f, base[PL + o], 0.2989f * base[o]));
      }
    float s[27];
    float cs;
    st_from_gray(gr, s, cs);
    if (isx) {
      store_row28(p1 + (size_t)gid * RS, s, cs);
    } else {
      size_t crow = (size_t)b * MALL + p;
      store_row28(p2c + crow * RS, s, cs);
      pack_row_frag(s, -cs, Cp + (crow >> 4) * 512, (int)(crow & 15));
    }
  } else {
    int row;
    float gr[9];
    if (bid < 144) {
      int q = (bid - 128) * 256 + t;  // [0, 4096)
      int b = q >> 10, p = q & 1023;
      int hb = p >> 5, wb = p & 31;
      const float* im = gt + (size_t)b * 3 * PL;
#pragma unroll
      for (int y = 0; y < 3; ++y)
#pragma unroll
        for (int xx = 0; xx < 3; ++xx)
          gr[y * 3 + xx] = bicubic_gray(im, 3 * hb + y, 3 * wb + xx, 2, -1);
      row = b * MALL + NP1 + p;
    } else {
      int q = (bid - 144) * 256 + t;  // [0, 1024)
      int b = q >> 8, p = q & 255;
      int hb = p >> 4, wb = p & 15;
      const float* im = gt + (size_t)b * 3 * PL;
#pragma unroll
      for (int y = 0; y < 3; ++y)
#pragma unroll
        for (int xx = 0; xx < 3; ++xx)
          gr[y * 3 + xx] = bicubic_gray(im, 3 * hb + y, 3 * wb + xx, 4, 0);
      row = b * MALL + NP1 + 1024 + p;
    }
    float s[27];
    float cs;
    st_from_gray(gr, s, cs);
    store_row28(p2c + (size_t)row * RS, s, cs);
    pack_row_frag(s, -cs, Cp + ((size_t)row >> 4) * 512, row & 15);
  }
}

// ---------------- K2: pack Q = p1 + p2 (needs both -> separate kernel) ------------
__global__ void __launch_bounds__(256) pack_q_kernel(
    const float* __restrict__ p1, const float* __restrict__ p2c,
    unsigned* __restrict__ Qp) {
  int gid = blockIdx.x * 256 + threadIdx.x;  // [0, 16384)
  int b = gid >> 12, n = gid & (NP1 - 1);
  const float* a = p1 + (size_t)gid * RS;
  const float* c = p2c + ((size_t)b * MALL + n) * RS;
  float v[27];
#pragma unroll
  for (int d = 0; d < 27; ++d) v[d] = a[d] + c[d];
  pack_row_frag(v, 1.0f, Qp + (size_t)(gid >> 4) * 512, gid & 15);
}

// ---------------- K3: MFMA argmax of t = 4 + q.c - |c|^2 via packed keys ----------
// 256-thread blocks, 4 waves; wave w owns rows nbase..nbase+31 (2 n-tiles) to keep
// VGPR pressure ~54 (< 64 => 8 waves/SIMD, NO launch_bounds cap, NO spill).
// Grid (32, NCHUNK, BATCH) = 2048 blocks. D mapping (16x16x32): col=lane&15 (m),
// row=(lane>>4)*4+reg. key = (bits(score+4) & ~31) | (TPC-1-iter): v_max_u32
// running argmax; earlier iter wins ties => first-argmin after chunk combine.
__global__ void __launch_bounds__(256) argmin_mfma_kernel(
    const unsigned* __restrict__ Qp, const unsigned* __restrict__ Cp,
    unsigned* __restrict__ pkey, int* __restrict__ pidx) {
  const int lane = threadIdx.x & 63;
  const int w = threadIdx.x >> 6;
  const int chunk = blockIdx.y;
  const int b = blockIdx.z;
  const int nbase = blockIdx.x * 128 + w * 32;  // wave owns 32 rows = 2 n-tiles
  const int lm = lane & 15, lg = lane >> 4;

  bf16x8 qh[2], ql[2];
#pragma unroll
  for (int t = 0; t < 2; ++t) {
    const unsigned* tb = Qp + (size_t)((b * NP1 + nbase) >> 4) * 512 + (size_t)t * 512 + lane * 4;
    qh[t] = *reinterpret_cast<const bf16x8*>(tb);
    ql[t] = *reinterpret_cast<const bf16x8*>(tb + 256);
  }

  unsigned keys[2][4];
#pragma unroll
  for (int t = 0; t < 2; ++t)
#pragma unroll
    for (int r = 0; r < 4; ++r) keys[t][r] = 0u;

  const int tile0 = chunk * TPC;
  const unsigned* cb = Cp + (size_t)(b * (MALL >> 4) + tile0) * 512 + lane * 4;
  bf16x8 ch = *reinterpret_cast<const bf16x8*>(cb);
  bf16x8 cl = *reinterpret_cast<const bf16x8*>(cb + 256);
  for (int i = 0; i < TPC; ++i) {
    cb += 512;
    // prefetch next tile (last iter reads the pad tile after Cp -- harmless)
    bf16x8 nh = *reinterpret_cast<const bf16x8*>(cb);
    bf16x8 nl = *reinterpret_cast<const bf16x8*>(cb + 256);
    const unsigned tag = (unsigned)(TPC - 1 - i);
#pragma unroll
    for (int t = 0; t < 2; ++t) {
      f32x4 a = {4.f, 4.f, 4.f, 4.f};  // +4 bias: scores in [-3,1] -> positive floats
      a = __builtin_amdgcn_mfma_f32_16x16x32_bf16(qh[t], ch, a, 0, 0, 0);
      a = __builtin_amdgcn_mfma_f32_16x16x32_bf16(ql[t], ch, a, 0, 0, 0);
      a = __builtin_amdgcn_mfma_f32_16x16x32_bf16(qh[t], cl, a, 0, 0, 0);
#pragma unroll
      for (int r = 0; r < 4; ++r) {
        unsigned kb = (__builtin_bit_cast(unsigned, (float)a[r]) & 0xFFFFFFE0u) | tag;
        keys[t][r] = keys[t][r] > kb ? keys[t][r] : kb;
      }
    }
    ch = nh;
    cl = nl;
  }

  // reduce (key, m) across the 16 lanes of each row-group; min m on key ties
#pragma unroll
  for (int t = 0; t < 2; ++t)
#pragma unroll
    for (int r = 0; r < 4; ++r) {
      unsigned k = keys[t][r];
      int m = (tile0 + (int)((unsigned)(TPC - 1) - (k & 31u))) * 16 + lm;
#pragma unroll
      for (int mk = 1; mk < 16; mk <<= 1) {
        unsigned ok = (unsigned)__shfl_xor((int)k, mk, 64);
        int om = __shfl_xor(m, mk, 64);
        bool take = (ok > k) || (ok == k && om < m);
        k = take ? ok : k;
        m = take ? om : m;
      }
      if (lm == 0) {
        int row = nbase + t * 16 + lg * 4 + r;
        size_t o = ((size_t)(b * NP1 + row)) * NCHUNK + chunk;
        pkey[o] = k & 0xFFFFFFE0u;  // masked: cross-chunk strict '>' keeps earliest chunk
        pidx[o] = m;
      }
    }
}

// ---------------- K4: combine partials, gather, L1 partials, ticketed final sum ---
__global__ void __launch_bounds__(256) finalize_kernel(
    const float* __restrict__ p1, const float* __restrict__ p2c,
    const unsigned* __restrict__ pkey, const int* __restrict__ pidx,
    float* __restrict__ bsum, unsigned* __restrict__ ctr, float* __restrict__ out) {
  int g = blockIdx.x * 256 + threadIdx.x;  // [0, BATCH*NP1)
  unsigned bk = 0u;
  int bi = 0;
  for (int ms = 0; ms < NCHUNK; ++ms) {
    unsigned k = pkey[(size_t)g * NCHUNK + ms];
    int ix = pidx[(size_t)g * NCHUNK + ms];
    bool gg = k > bk;  // strict > + ascending chunks => first-argmin tie-break
    bk = gg ? k : bk;
    bi = gg ? ix : bi;
  }
  int b = g >> 12;
  const float* a = p1 + (size_t)g * RS;
  const float* s2 = p2c + ((size_t)b * MALL + bi) * RS;
  float acc = 0.f;
#pragma unroll
  for (int d = 0; d < 27; ++d) acc += fabsf(a[d] - s2[d]);

  __shared__ float red[256];
  red[threadIdx.x] = acc;
  __syncthreads();
  for (int st = 128; st > 0; st >>= 1) {
    if (threadIdx.x < st) red[threadIdx.x] += red[threadIdx.x + st];
    __syncthreads();
  }
  if (threadIdx.x == 0) {
    __hip_atomic_store(&bsum[blockIdx.x], red[0], __ATOMIC_RELEASE, __HIP_MEMORY_SCOPE_AGENT);
    unsigned prev = __hip_atomic_fetch_add(ctr, 1u, __ATOMIC_ACQ_REL, __HIP_MEMORY_SCOPE_AGENT);
    if (prev == 63) {  // last of 64 blocks: deterministic ascending-order sum
      float s = 0.f;
      for (int i = 0; i < 64; ++i)
        s += __hip_atomic_load(&bsum[i], __ATOMIC_ACQUIRE, __HIP_MEMORY_SCOPE_AGENT);
      out[0] = s * (1.0f / 442368.0f);
    }
  }
}

}  // namespace

extern "C" void kernel_launch(void* const* d_in, const int* in_sizes, int n_in,
                              void* d_out, int out_size, void* d_ws, size_t ws_size,
                              hipStream_t stream) {
  const float* x  = (const float*)d_in[0];
  const float* gt = (const float*)d_in[1];
  float* out = (float*)d_out;

  // workspace layout (4-byte slots)
  float* ws = (float*)d_ws;
  float* p1   = ws;                                              // 4*4096*28
  float* p2c  = p1 + (size_t)BATCH * NP1 * RS;                   // 4*5376*28
  unsigned* Qp = (unsigned*)(p2c + (size_t)BATCH * MALL * RS);   // 4*4096*32
  unsigned* Cp = Qp + (size_t)BATCH * NP1 * 32;                  // 4*5376*32 + 512 pad
  unsigned* pkey = Cp + (size_t)BATCH * MALL * 32 + 512;         // 4*4096*16
  int*   pidx   = (int*)(pkey + (size_t)BATCH * NP1 * NCHUNK);   // 4*4096*16
  float* bsum   = (float*)(pidx + (size_t)BATCH * NP1 * NCHUNK); // 64
  unsigned* ctr = (unsigned*)(bsum + 64);                        // 1

  // K1: fused front end (148 blocks)
  prep_all_kernel<<<148, 256, 0, stream>>>(x, gt, p1, p2c, Cp, ctr);

  // K2: Q = p1 + p2 pack (64 blocks)
  pack_q_kernel<<<64, 256, 0, stream>>>(p1, p2c, Qp);

  // K3: MFMA chunked argmax (2 n-tiles/wave, ~54 VGPR, no spill)
  {
    dim3 grid(32, NCHUNK, BATCH);
    argmin_mfma_kernel<<<grid, 256, 0, stream>>>(Qp, Cp, pkey, pidx);
  }

  // K4: combine chunks + L1 loss + ticketed deterministic final sum
  finalize_kernel<<<64, 256, 0, stream>>>(p1, p2c, pkey, pidx, bsum, ctr, out);
}

// Round 8
// 60.653 us; speedup vs baseline: 2.8127x; 1.5033x over previous
//
#include <hip/hip_runtime.h>
#include <hip/hip_bf16.h>
#include <math.h>

// ---------------- problem constants ----------------
namespace {
constexpr int BATCH = 4;
constexpr int IMG   = 192;
constexpr int PL    = IMG * IMG;
constexpr int NP1   = 4096;   // 64*64 full-res patches per image
constexpr int MALL  = 5376;   // 4096 + 1024 + 256 candidate patches
constexpr int RS    = 28;     // fp32 row stride: 27 values + |c|^2 slot
constexpr int NCHUNK = 16;    // m-chunks for argmin partials
constexpr int TPC    = 21;    // 16-wide m-tiles per chunk (16*21*16 = 5376)

// gaussian kernel constants (float32 images of the numpy float32 values)
#define GA 0.27406862f   // gauss1d(1.0) edge
#define GB 0.45186276f   // gauss1d(1.0) center
#define RC 0.33277732f   // gauss1d(10.0) edge
#define RD 0.33444537f   // gauss1d(10.0) center

typedef __bf16 bf16x8 __attribute__((ext_vector_type(8)));
typedef float  f32x4  __attribute__((ext_vector_type(4)));

__device__ __forceinline__ void conv3(const float in[9], const float k[9], float out[9]) {
#pragma unroll
  for (int y = 0; y < 3; ++y)
#pragma unroll
    for (int x = 0; x < 3; ++x) {
      float s = 0.f;
#pragma unroll
      for (int i = 0; i < 3; ++i) {
        int yy = y + i - 1;
        if (yy < 0 || yy > 2) continue;
#pragma unroll
        for (int j = 0; j < 3; ++j) {
          int xx = x + j - 1;
          if (xx < 0 || xx > 2) continue;
          s = fmaf(k[i * 3 + j], in[yy * 3 + xx], s);
        }
      }
      out[y * 3 + x] = s;
    }
}

// gray -> normalized structure-tensor 27-vector + |c|^2 of the normalized vec
__device__ __forceinline__ void st_from_gray(const float gray[9], float stv[27], float& cs) {
  const float KX[9] = {GA * GA, 0.f, -GA * GA, GB * GA, 0.f, -GB * GA, GA * GA, 0.f, -GA * GA};
  const float KY[9] = {GA * GA, GA * GB, GA * GA, 0.f, 0.f, 0.f, -GA * GA, -GA * GB, -GA * GA};
  const float KS[9] = {RC * RC, RC * RD, RC * RC, RD * RC, RD * RD, RD * RC, RC * RC, RC * RD, RC * RC};
  float Ix[9], Iy[9];
  conv3(gray, KX, Ix);
  conv3(gray, KY, Iy);
  float Pxx[9], Pyy[9], Pxy[9];
#pragma unroll
  for (int t = 0; t < 9; ++t) {
    Pxx[t] = Ix[t] * Ix[t];
    Pyy[t] = Iy[t] * Iy[t];
    Pxy[t] = Ix[t] * Iy[t];
  }
  conv3(Pxx, KS, stv + 0);
  conv3(Pyy, KS, stv + 9);
  conv3(Pxy, KS, stv + 18);
  float s2 = 0.f;
#pragma unroll
  for (int d = 0; d < 27; ++d) s2 = fmaf(stv[d], stv[d], s2);
  float inv = 1.0f / (sqrtf(s2) + 1e-12f);
  float c = 0.f;
#pragma unroll
  for (int d = 0; d < 27; ++d) {
    stv[d] *= inv;
    c = fmaf(stv[d], stv[d], c);
  }
  cs = c;
}

// ---------------- bicubic taps (jax.image.resize, antialias=False) ----------------
__device__ __forceinline__ void mkw(int k0, int IS, float w[4], int k[4]) {
  const float W4[4] = {-0.0625f, 0.5625f, 0.5625f, -0.0625f};
  float ssum = 0.f;
#pragma unroll
  for (int u = 0; u < 4; ++u) {
    int kk = k0 + u;
    bool v = (kk >= 0) && (kk < IS);
    w[u] = v ? W4[u] : 0.f;
    k[u] = v ? kk : 0;
    ssum += w[u];
  }
  float inv = 1.f / ssum;  // interior: exactly 1.0
#pragma unroll
  for (int u = 0; u < 4; ++u) w[u] *= inv;
}

// resized-grayscale pixel straight from the 3-channel 192x192 image
// (resize and grayscale are both linear -> they commute; validated, absmax 0)
__device__ __forceinline__ float bicubic_gray(const float* __restrict__ im,
                                              int i, int j, int step, int koff) {
  float wr[4], wc[4];
  int kr[4], kc[4];
  mkw(step * i + koff, IMG, wr, kr);
  mkw(step * j + koff, IMG, wc, kc);
  float acc = 0.f;
#pragma unroll
  for (int u = 0; u < 4; ++u) {
    float rs = 0.f;
#pragma unroll
    for (int v = 0; v < 4; ++v) {
      int o = kr[u] * IMG + kc[v];
      float gy = fmaf(0.114f, im[2 * PL + o], fmaf(0.587f, im[PL + o], 0.2989f * im[o]));
      rs = fmaf(wc[v], gy, rs);
    }
    acc = fmaf(wr[u], rs, acc);
  }
  return acc;
}

// ---------------- fragment-major bf16 hi/lo pack ----------------
// Tile = 16 rows = 512 uints (2 KB): hi half uints 0..255, lo half 256..511.
// Row rl, k-group lg -> uint4 at (lg*16+rl)*4 (hi) / 256+(lg*16+rl)*4 (lo).
// In argmin, lane l reads uint4 at tile_base + l*4 -> fully coalesced.
__device__ __forceinline__ void pack_row_frag(const float* __restrict__ v, float tail,
                                              unsigned* __restrict__ base, int rl) {
  unsigned uh[16], ul[16];
#pragma unroll
  for (int p = 0; p < 16; ++p) {
    float a  = (2 * p < 27) ? v[2 * p] : 0.f;
    float bb = (2 * p + 1 < 27) ? v[2 * p + 1] : (2 * p + 1 == 27 ? tail : 0.f);
    __hip_bfloat16 ah = __float2bfloat16(a);
    __hip_bfloat16 bh = __float2bfloat16(bb);
    float af = __bfloat162float(ah), bf2 = __bfloat162float(bh);
    __hip_bfloat16 al = __float2bfloat16(a - af);
    __hip_bfloat16 bl = __float2bfloat16(bb - bf2);
    uh[p] = ((unsigned)__builtin_bit_cast(unsigned short, bh) << 16) |
            (unsigned)__builtin_bit_cast(unsigned short, ah);
    ul[p] = ((unsigned)__builtin_bit_cast(unsigned short, bl) << 16) |
            (unsigned)__builtin_bit_cast(unsigned short, al);
  }
#pragma unroll
  for (int lg = 0; lg < 4; ++lg) {
    *reinterpret_cast<uint4*>(base + (size_t)(lg * 16 + rl) * 4) =
        make_uint4(uh[4 * lg], uh[4 * lg + 1], uh[4 * lg + 2], uh[4 * lg + 3]);
    *reinterpret_cast<uint4*>(base + 256 + (size_t)(lg * 16 + rl) * 4) =
        make_uint4(ul[4 * lg], ul[4 * lg + 1], ul[4 * lg + 2], ul[4 * lg + 3]);
  }
}

__device__ __forceinline__ void store_row28(float* __restrict__ dst, const float v[27], float tail) {
  float4* d4 = reinterpret_cast<float4*>(dst);
#pragma unroll
  for (int i = 0; i < 6; ++i)
    d4[i] = make_float4(v[4 * i], v[4 * i + 1], v[4 * i + 2], v[4 * i + 3]);
  d4[6] = make_float4(v[24], v[25], v[26], tail);
}

// ---------------- K1: fused front end (block-range dispatch, one st per thread) ----
__global__ void __launch_bounds__(256) prep_all_kernel(
    const float* __restrict__ x, const float* __restrict__ gt,
    float* __restrict__ p1, float* __restrict__ p2c,
    unsigned* __restrict__ Cp, unsigned* __restrict__ ctr) {
  const int bid = blockIdx.x;
  const int t = threadIdx.x;
  if (bid == 0 && t == 0) ctr[0] = 0;  // reset finalize ticket (stream-ordered)

  if (bid < 128) {
    const bool isx = bid < 64;
    const int gid = (isx ? bid : bid - 64) * 256 + t;  // [0, 16384)
    const int b = gid >> 12, p = gid & (NP1 - 1);
    const int hb = p >> 6, wb = p & 63;
    const float* base = (isx ? x : gt) + (size_t)b * 3 * PL + (size_t)(hb * 3) * IMG + wb * 3;
    float gr[9];
#pragma unroll
    for (int y = 0; y < 3; ++y)
#pragma unroll
      for (int xx = 0; xx < 3; ++xx) {
        int o = y * IMG + xx;
        gr[y * 3 + xx] = fmaf(0.114f, base[2 * PL + o],
                              fmaf(0.587f, base[PL + o], 0.2989f * base[o]));
      }
    float s[27];
    float cs;
    st_from_gray(gr, s, cs);
    if (isx) {
      store_row28(p1 + (size_t)gid * RS, s, cs);
    } else {
      size_t crow = (size_t)b * MALL + p;
      store_row28(p2c + crow * RS, s, cs);
      pack_row_frag(s, -cs, Cp + (crow >> 4) * 512, (int)(crow & 15));
    }
  } else {
    int row;
    float gr[9];
    if (bid < 144) {
      int q = (bid - 128) * 256 + t;  // [0, 4096)
      int b = q >> 10, p = q & 1023;
      int hb = p >> 5, wb = p & 31;
      const float* im = gt + (size_t)b * 3 * PL;
#pragma unroll
      for (int y = 0; y < 3; ++y)
#pragma unroll
        for (int xx = 0; xx < 3; ++xx)
          gr[y * 3 + xx] = bicubic_gray(im, 3 * hb + y, 3 * wb + xx, 2, -1);
      row = b * MALL + NP1 + p;
    } else {
      int q = (bid - 144) * 256 + t;  // [0, 1024)
      int b = q >> 8, p = q & 255;
      int hb = p >> 4, wb = p & 15;
      const float* im = gt + (size_t)b * 3 * PL;
#pragma unroll
      for (int y = 0; y < 3; ++y)
#pragma unroll
        for (int xx = 0; xx < 3; ++xx)
          gr[y * 3 + xx] = bicubic_gray(im, 3 * hb + y, 3 * wb + xx, 4, 0);
      row = b * MALL + NP1 + 1024 + p;
    }
    float s[27];
    float cs;
    st_from_gray(gr, s, cs);
    store_row28(p2c + (size_t)row * RS, s, cs);
    pack_row_frag(s, -cs, Cp + ((size_t)row >> 4) * 512, row & 15);
  }
}

// ---------------- K2: pack Q = p1 + p2 (needs both -> separate kernel) ------------
__global__ void __launch_bounds__(256) pack_q_kernel(
    const float* __restrict__ p1, const float* __restrict__ p2c,
    unsigned* __restrict__ Qp) {
  int gid = blockIdx.x * 256 + threadIdx.x;  // [0, 16384)
  int b = gid >> 12, n = gid & (NP1 - 1);
  const float* a = p1 + (size_t)gid * RS;
  const float* c = p2c + ((size_t)b * MALL + n) * RS;
  float v[27];
#pragma unroll
  for (int d = 0; d < 27; ++d) v[d] = a[d] + c[d];
  pack_row_frag(v, 1.0f, Qp + (size_t)(gid >> 4) * 512, gid & 15);
}

// ---------------- K3: MFMA argmax of t = 4 + q.c - |c|^2, LDS-staged C ------------
// 256-thread blocks (4 waves); wave w owns rows bx*256 + w*64 (4 n-tiles, 12 MFMAs
// per C-tile -> high arithmetic intensity). All 4 waves share each C tile via LDS
// (double-buffered 2 KB tiles, reg-staged uint2/thread). No launch_bounds cap, no
// deep manual prefetch -> VGPR should stay < 128 (>= 4 waves/SIMD, no spill).
// Grid (16, NCHUNK, BATCH) = 1024 blocks. D mapping (16x16x32): col=lane&15 (m),
// row=(lane>>4)*4+reg. key = (bits(score+4) & ~31) | (TPC-1-i): v_max_u32 running
// argmax; earlier tile wins ties => first-argmin after chunk combine.
__global__ void __launch_bounds__(256) argmin_mfma_kernel(
    const unsigned* __restrict__ Qp, const unsigned* __restrict__ Cp,
    unsigned* __restrict__ pkey, int* __restrict__ pidx) {
  const int lane = threadIdx.x & 63;
  const int w = threadIdx.x >> 6;
  const int chunk = blockIdx.y;
  const int b = blockIdx.z;
  const int nbase = blockIdx.x * 256 + w * 64;
  const int lm = lane & 15, lg = lane >> 4;

  __shared__ unsigned cbuf[2][512];  // two 2 KB C tiles (hi 0..255, lo 256..511)

  bf16x8 qh[4], ql[4];
#pragma unroll
  for (int t = 0; t < 4; ++t) {
    const unsigned* tb = Qp + (size_t)((b * NP1 + nbase) >> 4) * 512 + (size_t)t * 512 + lane * 4;
    qh[t] = *reinterpret_cast<const bf16x8*>(tb);
    ql[t] = *reinterpret_cast<const bf16x8*>(tb + 256);
  }

  unsigned keys[4][4];
#pragma unroll
  for (int t = 0; t < 4; ++t)
#pragma unroll
    for (int r = 0; r < 4; ++r) keys[t][r] = 0u;

  const int tile0 = chunk * TPC;
  const unsigned* ct = Cp + (size_t)(b * (MALL >> 4) + tile0) * 512;

  // stage tile 0
  {
    uint2 s0 = *reinterpret_cast<const uint2*>(ct + 2 * threadIdx.x);
    *reinterpret_cast<uint2*>(&cbuf[0][2 * threadIdx.x]) = s0;
  }
  __syncthreads();

  for (int i = 0; i < TPC; ++i) {
    uint2 nx;
    if (i + 1 < TPC)
      nx = *reinterpret_cast<const uint2*>(ct + (size_t)(i + 1) * 512 + 2 * threadIdx.x);

    const unsigned* cb = &cbuf[i & 1][0];
    bf16x8 ch = *reinterpret_cast<const bf16x8*>(cb + lane * 4);
    bf16x8 cl = *reinterpret_cast<const bf16x8*>(cb + 256 + lane * 4);
    const unsigned tag = (unsigned)(TPC - 1 - i);
#pragma unroll
    for (int t = 0; t < 4; ++t) {
      f32x4 a = {4.f, 4.f, 4.f, 4.f};  // +4 bias: scores in [-3,1] -> positive floats
      a = __builtin_amdgcn_mfma_f32_16x16x32_bf16(qh[t], ch, a, 0, 0, 0);
      a = __builtin_amdgcn_mfma_f32_16x16x32_bf16(ql[t], ch, a, 0, 0, 0);
      a = __builtin_amdgcn_mfma_f32_16x16x32_bf16(qh[t], cl, a, 0, 0, 0);
#pragma unroll
      for (int r = 0; r < 4; ++r) {
        unsigned kb = (__builtin_bit_cast(unsigned, (float)a[r]) & 0xFFFFFFE0u) | tag;
        keys[t][r] = keys[t][r] > kb ? keys[t][r] : kb;
      }
    }
    if (i + 1 < TPC) {
      __syncthreads();  // all waves done reading buf[(i+1)&1] (from iter i-1)
      *reinterpret_cast<uint2*>(&cbuf[(i + 1) & 1][2 * threadIdx.x]) = nx;
      __syncthreads();  // writes visible before iter i+1 reads
    }
  }

  // reduce (key, m) across the 16 lanes of each row-group; min m on key ties
#pragma unroll
  for (int t = 0; t < 4; ++t)
#pragma unroll
    for (int r = 0; r < 4; ++r) {
      unsigned k = keys[t][r];
      int m = (tile0 + (int)((unsigned)(TPC - 1) - (k & 31u))) * 16 + lm;
#pragma unroll
      for (int mk = 1; mk < 16; mk <<= 1) {
        unsigned ok = (unsigned)__shfl_xor((int)k, mk, 64);
        int om = __shfl_xor(m, mk, 64);
        bool take = (ok > k) || (ok == k && om < m);
        k = take ? ok : k;
        m = take ? om : m;
      }
      if (lm == 0) {
        int row = nbase + t * 16 + lg * 4 + r;
        size_t o = ((size_t)(b * NP1 + row)) * NCHUNK + chunk;
        pkey[o] = k & 0xFFFFFFE0u;  // masked: cross-chunk strict '>' keeps earliest chunk
        pidx[o] = m;
      }
    }
}

// ---------------- K4: combine partials, gather, L1 partials, ticketed final sum ---
__global__ void __launch_bounds__(256) finalize_kernel(
    const float* __restrict__ p1, const float* __restrict__ p2c,
    const unsigned* __restrict__ pkey, const int* __restrict__ pidx,
    float* __restrict__ bsum, unsigned* __restrict__ ctr, float* __restrict__ out) {
  int g = blockIdx.x * 256 + threadIdx.x;  // [0, BATCH*NP1)
  unsigned bk = 0u;
  int bi = 0;
  for (int ms = 0; ms < NCHUNK; ++ms) {
    unsigned k = pkey[(size_t)g * NCHUNK + ms];
    int ix = pidx[(size_t)g * NCHUNK + ms];
    bool gg = k > bk;  // strict > + ascending chunks => first-argmin tie-break
    bk = gg ? k : bk;
    bi = gg ? ix : bi;
  }
  int b = g >> 12;
  const float* a = p1 + (size_t)g * RS;
  const float* s2 = p2c + ((size_t)b * MALL + bi) * RS;
  float acc = 0.f;
#pragma unroll
  for (int d = 0; d < 27; ++d) acc += fabsf(a[d] - s2[d]);

  __shared__ float red[256];
  red[threadIdx.x] = acc;
  __syncthreads();
  for (int st = 128; st > 0; st >>= 1) {
    if (threadIdx.x < st) red[threadIdx.x] += red[threadIdx.x + st];
    __syncthreads();
  }
  if (threadIdx.x == 0) {
    __hip_atomic_store(&bsum[blockIdx.x], red[0], __ATOMIC_RELEASE, __HIP_MEMORY_SCOPE_AGENT);
    unsigned prev = __hip_atomic_fetch_add(ctr, 1u, __ATOMIC_ACQ_REL, __HIP_MEMORY_SCOPE_AGENT);
    if (prev == 63) {  // last of 64 blocks: deterministic ascending-order sum
      float s = 0.f;
      for (int i = 0; i < 64; ++i)
        s += __hip_atomic_load(&bsum[i], __ATOMIC_ACQUIRE, __HIP_MEMORY_SCOPE_AGENT);
      out[0] = s * (1.0f / 442368.0f);
    }
  }
}

}  // namespace

extern "C" void kernel_launch(void* const* d_in, const int* in_sizes, int n_in,
                              void* d_out, int out_size, void* d_ws, size_t ws_size,
                              hipStream_t stream) {
  const float* x  = (const float*)d_in[0];
  const float* gt = (const float*)d_in[1];
  float* out = (float*)d_out;

  // workspace layout (4-byte slots)
  float* ws = (float*)d_ws;
  float* p1   = ws;                                              // 4*4096*28
  float* p2c  = p1 + (size_t)BATCH * NP1 * RS;                   // 4*5376*28
  unsigned* Qp = (unsigned*)(p2c + (size_t)BATCH * MALL * RS);   // 4*4096*32
  unsigned* Cp = Qp + (size_t)BATCH * NP1 * 32;                  // 4*5376*32 + 512 pad
  unsigned* pkey = Cp + (size_t)BATCH * MALL * 32 + 512;         // 4*4096*16
  int*   pidx   = (int*)(pkey + (size_t)BATCH * NP1 * NCHUNK);   // 4*4096*16
  float* bsum   = (float*)(pidx + (size_t)BATCH * NP1 * NCHUNK); // 64
  unsigned* ctr = (unsigned*)(bsum + 64);                        // 1

  // K1: fused front end (148 blocks)
  prep_all_kernel<<<148, 256, 0, stream>>>(x, gt, p1, p2c, Cp, ctr);

  // K2: Q = p1 + p2 pack (64 blocks)
  pack_q_kernel<<<64, 256, 0, stream>>>(p1, p2c, Qp);

  // K3: MFMA chunked argmax (LDS-staged C tiles, 4 n-tiles/wave)
  {
    dim3 grid(16, NCHUNK, BATCH);
    argmin_mfma_kernel<<<grid, 256, 0, stream>>>(Qp, Cp, pkey, pidx);
  }

  // K4: combine chunks + L1 loss + ticketed deterministic final sum
  finalize_kernel<<<64, 256, 0, stream>>>(p1, p2c, pkey, pidx, bsum, ctr, out);
}